// Round 14
// baseline (3365.934 us; speedup 1.0000x reference)
//
#include <hip/hip_runtime.h>
#include <hip/hip_bf16.h>
#include <cstdint>
#include <cstddef>

// Problem constants (B=4, T=2048, DIM=2048, S=4, DFF=8192)
#define DIM   2048
#define DFF   8192
#define NROWS 8192   // B*T
#define NFOLD 24     // 4 (pre) + 4 (post) + 16 (res)

typedef float f32x4 __attribute__((ext_vector_type(4)));
typedef __bf16 bf16x8 __attribute__((ext_vector_type(8)));

__device__ __forceinline__ float sigmoidf_(float v) { return 1.0f / (1.0f + expf(-v)); }

__device__ __forceinline__ unsigned short f2bf(float v) {
    union { __hip_bfloat16 h; unsigned short u; } cv;
    cv.h = __float2bfloat16(v);
    return cv.u;
}

__device__ __forceinline__ void async_copy16(const void* g, void* l) {
    __builtin_amdgcn_global_load_lds((const __attribute__((address_space(1))) void*)g,
                                     (__attribute__((address_space(3))) void*)l, 16, 0, 0);
}

// Raw workgroup barrier WITHOUT waitcnt drain (keeps global_load_lds in flight).
__device__ __forceinline__ void wg_barrier() {
    asm volatile("" ::: "memory");
    __builtin_amdgcn_s_barrier();
    asm volatile("" ::: "memory");
}

#define VM(n)  asm volatile("s_waitcnt vmcnt(" #n ")" ::: "memory")
#define LGKM0  asm volatile("s_waitcnt lgkmcnt(0)" ::: "memory")
#define LGKM8  asm volatile("s_waitcnt lgkmcnt(8)" ::: "memory")
// ROUND 14: occupancy A/B. All seven lockstep 1-block/CU schedules (r7-r13)
// sit at 5.5k cyc/tile = serial(LDS port 3.1k + MFMA 2.5k). GEMM1 tests a
// 64 KiB-LDS BK=32 variant (2 blocks/CU, 2 barriers/K-step) so a second
// block's MFMA covers this block's port/barrier windows (m114 co-schedule).
// GEMM2 keeps the best-measured r9 kernel as the in-probe control.

// ---------------------------------------------------------------------------
// Fold phi weights: Wfold[r][d] = sum_{j<4} src[r][j*DIM + d], r in [0,24)
// ---------------------------------------------------------------------------
__global__ __launch_bounds__(256) void fold_kernel(const float* __restrict__ pre_w,
                                                   const float* __restrict__ post_w,
                                                   const float* __restrict__ res_w,
                                                   float* __restrict__ Wfold) {
    int idx = blockIdx.x * 256 + threadIdx.x;
    if (idx >= NFOLD * DIM) return;
    int r = idx >> 11;          // /DIM
    int d = idx & (DIM - 1);
    const float* src;
    if (r < 4)      src = pre_w  + (size_t)r * (4 * DIM);
    else if (r < 8) src = post_w + (size_t)(r - 4) * (4 * DIM);
    else            src = res_w  + (size_t)(r - 8) * (4 * DIM);
    Wfold[idx] = src[d] + src[DIM + d] + src[2 * DIM + d] + src[3 * DIM + d];
}

// ---------------------------------------------------------------------------
// Transpose f32 [R][C] -> bf16 [C][R]
// ---------------------------------------------------------------------------
__global__ __launch_bounds__(256) void transpose_to_bf16(const float* __restrict__ in,
                                                         __hip_bfloat16* __restrict__ out,
                                                         int R, int C) {
    __shared__ float tile[32][33];
    int bx = blockIdx.x, by = blockIdx.y;
    int tx = threadIdx.x & 31, ty0 = threadIdx.x >> 5;
#pragma unroll
    for (int i = 0; i < 4; i++) {
        int ty = ty0 + i * 8;
        tile[ty][tx] = in[(size_t)(by * 32 + ty) * C + bx * 32 + tx];
    }
    __syncthreads();
#pragma unroll
    for (int i = 0; i < 4; i++) {
        int ty = ty0 + i * 8;
        out[(size_t)(bx * 32 + ty) * R + by * 32 + tx] = __float2bfloat16(tile[tx][ty]);
    }
}

// ---------------------------------------------------------------------------
// Gating: wave-per-row, 8 rows per block (512 threads).
// ---------------------------------------------------------------------------
__global__ __launch_bounds__(512) void gating_kernel(
    const float* __restrict__ x, const float* __restrict__ Wfold,
    const float* __restrict__ phi_pre_b, const float* __restrict__ phi_post_b,
    const float* __restrict__ phi_res_b,
    const float* __restrict__ alpha_pre, const float* __restrict__ alpha_post,
    const float* __restrict__ alpha_res,
    const float* __restrict__ b_pre, const float* __restrict__ b_post,
    const float* __restrict__ b_res,
    __hip_bfloat16* __restrict__ Abuf,
    float* __restrict__ g_res_arr, float* __restrict__ g_post_arr) {
    const int tid = threadIdx.x;
    const int lane = tid & 63, wave = tid >> 6;
    const int row = blockIdx.x * 8 + wave;

    const float4* x4 = (const float4*)x + (size_t)row * 512;
    const float4* w4 = (const float4*)Wfold;

    float4 xv[8];
#pragma unroll
    for (int j = 0; j < 8; j++) xv[j] = x4[j * 64 + lane];

    float p[25];
    p[24] = 0.f;
#pragma unroll
    for (int j = 0; j < 8; j++)
        p[24] += xv[j].x * xv[j].x + xv[j].y * xv[j].y + xv[j].z * xv[j].z + xv[j].w * xv[j].w;

    for (int r = 0; r < NFOLD; r++) {
        float acc = 0.f;
#pragma unroll
        for (int j = 0; j < 8; j++) {
            float4 wv = w4[r * 512 + j * 64 + lane];
            acc += xv[j].x * wv.x + xv[j].y * wv.y + xv[j].z * wv.z + xv[j].w * wv.w;
        }
        p[r] = acc;
    }

#pragma unroll
    for (int r = 0; r < 25; r++) {
        float v = p[r];
#pragma unroll
        for (int off = 1; off < 64; off <<= 1) v += __shfl_xor(v, off, 64);
        p[r] = v;
    }

    const float rms = rsqrtf(p[24] / (float)DIM + 1.1920928955078125e-07f);
    const float ap = alpha_pre[0], aq = alpha_post[0], ar = alpha_res[0];
    float gpre = 0.f, gpost = 0.f;
#pragma unroll
    for (int s = 0; s < 4; s++) {
        gpre  += sigmoidf_(ap * (rms * p[s]     + phi_pre_b[s])  + b_pre[s]);
        gpost += 2.0f * sigmoidf_(aq * (rms * p[4 + s] + phi_post_b[s]) + b_post[s]);
    }
    float Mm[4][4];
#pragma unroll
    for (int i = 0; i < 4; i++)
#pragma unroll
        for (int j = 0; j < 4; j++) {
            int k = i * 4 + j;
            Mm[i][j] = expf(ar * (rms * p[8 + k] + phi_res_b[k]) + b_res[k]);
        }
    for (int it = 0; it < 10; ++it) {
#pragma unroll
        for (int i = 0; i < 4; i++) {
            float rs = 1.0f / (Mm[i][0] + Mm[i][1] + Mm[i][2] + Mm[i][3]);
#pragma unroll
            for (int j = 0; j < 4; j++) Mm[i][j] *= rs;
        }
#pragma unroll
        for (int j = 0; j < 4; j++) {
            float cs = 1.0f / (Mm[0][j] + Mm[1][j] + Mm[2][j] + Mm[3][j]);
#pragma unroll
            for (int i = 0; i < 4; i++) Mm[i][j] *= cs;
        }
    }
    float gres = 0.f;
#pragma unroll
    for (int i = 0; i < 4; i++)
#pragma unroll
        for (int j = 0; j < 4; j++) gres += Mm[i][j];

    __hip_bfloat16* arow = Abuf + (size_t)row * DIM;
#pragma unroll
    for (int j = 0; j < 8; j++) {
        ushort4 u;
        u.x = f2bf(xv[j].x * gpre); u.y = f2bf(xv[j].y * gpre);
        u.z = f2bf(xv[j].z * gpre); u.w = f2bf(xv[j].w * gpre);
        *reinterpret_cast<ushort4*>(arow + (j * 64 + lane) * 4) = u;
    }
    if (lane == 0) {
        g_res_arr[row]  = gres;
        g_post_arr[row] = gpost;
    }
}

// ===========================================================================
// VARIANT 1 (GEMM1): 256x256 bf16 GEMM, BK=32, 64 KiB LDS -> 2 blocks/CU.
//   8 waves (2M x 4N), per-wave out 128x64 (8m x 4n frags), 32 MFMA/tile.
// LDS per matrix: 2 x [256 rows][64 B] (16 KB buffers). Row r, 16B-slot s
// holds logical slot s ^ f(r), f(r) = (r>>1)&3  -> ds_read 2-way (free).
// global_load_lds writes linearly (lane l -> row l/4, slot l&3); per-lane
// global source pre-applies the inverse: col-group (l&3) ^ ((l>>3)&3).
// K-loop (2 barriers/tile): {rd 12; LGKM0; bar; stg(t+2); 32 MFMA; VM; bar}
//   WAR: stg(t+2) -> buf[t&1] issues after bar1, which follows every wave's
//   LGKM0-pinned reads of buf[t&1]. VM(4) at tile end drains t+1's 4 loads
//   (FIFO: outstanding = t+1(4)+t+2(4)); tail VM(0). Prologue stages t0,t1,
//   VM(4) lands t0.
// ===========================================================================
#define RD32_A                                                                    \
    _Pragma("unroll") for (int m = 0; m < 8; ++m)                                 \
        a3[m] = *(const bf16x8*)(Ac + baseA + m * 1024);
#define RD32_B                                                                    \
    _Pragma("unroll") for (int n = 0; n < 4; ++n)                                 \
        b3[n] = *(const bf16x8*)(Bc + baseB + n * 1024);
#define MQ32                                                                      \
    __builtin_amdgcn_s_setprio(1);                                                \
    _Pragma("unroll") for (int m = 0; m < 8; ++m)                                 \
    _Pragma("unroll") for (int n = 0; n < 4; ++n)                                 \
        acc[m][n] = __builtin_amdgcn_mfma_f32_16x16x32_bf16(a3[m], b3[n],         \
                                                            acc[m][n], 0, 0, 0); \
    __builtin_amdgcn_s_setprio(0);
#define STG32_A(t_)                                                               \
    if ((t_) < nk) {                                                              \
        char* l_ = ldsA + (((t_) & 1) * 16384) + wave * 2048 + (lane & 63) * 16;  \
        async_copy16(Ab + aO[0] + (size_t)(t_) * 64, l_);                         \
        async_copy16(Ab + aO[1] + (size_t)(t_) * 64, l_ + 1024);                  \
    }
#define STG32_B(t_)                                                               \
    if ((t_) < nk) {                                                              \
        char* l_ = ldsB + (((t_) & 1) * 16384) + wave * 2048 + (lane & 63) * 16;  \
        async_copy16(Bb + bO[0] + (size_t)(t_) * 64, l_);                         \
        async_copy16(Bb + bO[1] + (size_t)(t_) * 64, l_ + 1024);                  \
    }

template <int MODE, int NB>
__global__ __launch_bounds__(512, 4) void gemm256_bk32(
    const __hip_bfloat16* __restrict__ A, const __hip_bfloat16* __restrict__ Bt,
    int M, int N, int K, const float* __restrict__ bias,
    __hip_bfloat16* __restrict__ outh, float* __restrict__ outf,
    const float* __restrict__ x, const float* __restrict__ g_res,
    const float* __restrict__ g_post) {
    __shared__ __align__(16) char ldsA[32768];
    __shared__ __align__(16) char ldsB[32768];

    const int wg = blockIdx.x;
    const int xcd = wg & 7;
    const int i = wg >> 3;
    const int nt = xcd * NB + (i % NB);
    const int mt = i / NB;
    const int m0 = mt * 256;
    const int n0 = nt * 256;

    const int tid = threadIdx.x;
    const int lane = tid & 63;
    const int wave = tid >> 6;            // 0..7
    const int wr = wave >> 2;             // 0..1 (M)
    const int wc = wave & 3;              // 0..3 (N)
    const int q = lane >> 4;              // 0..3 (k-slot)
    const int r15 = lane & 15;

    // ds_read addressing: row*64 + ((q ^ f(row))<<4), f(row) = (r15>>1)&3
    const uint32_t cswz = (uint32_t)((q ^ ((r15 >> 1) & 3)) << 4);
    const uint32_t baseA = (uint32_t)((wr * 128 + r15) * 64) + cswz;
    const uint32_t baseB = (uint32_t)((wc * 64 + r15) * 64) + cswz;

    // staging: lane l -> row l>>2 (+i*16 +wave*32), slot l&3;
    // global col-group = (l&3) ^ f(row) = (l&3) ^ ((l>>3)&3)
    const int srow = wave * 32 + (lane >> 2);
    const uint32_t scg = (uint32_t)(((lane & 3) ^ ((lane >> 3) & 3)) << 4);
    const size_t K2 = (size_t)K * 2;
    size_t aO[2], bO[2];
#pragma unroll
    for (int ii = 0; ii < 2; ++ii) {
        aO[ii] = (size_t)(m0 + srow + ii * 16) * K2 + scg;
        bO[ii] = (size_t)(n0 + srow + ii * 16) * K2 + scg;
    }
    const char* Ab = (const char*)A;
    const char* Bb = (const char*)Bt;

    f32x4 acc[8][4];
#pragma unroll
    for (int m = 0; m < 8; ++m)
#pragma unroll
        for (int n = 0; n < 4; ++n) acc[m][n] = (f32x4){0.f, 0.f, 0.f, 0.f};

    const int nk = K / 32;

    STG32_A(0) STG32_B(0) STG32_A(1) STG32_B(1)
    VM(4);                                // tile 0 landed
    wg_barrier();

    bf16x8 a3[8], b3[4];

    for (int kt = 0; kt < nk; ++kt) {
        const char* Ac = ldsA + (kt & 1) * 16384;
        const char* Bc = ldsB + (kt & 1) * 16384;
        RD32_A
        RD32_B
        LGKM0;                            // own reads in regs
        wg_barrier();                     // all waves' reads done
        STG32_A(kt + 2) STG32_B(kt + 2)   // overwrite buf[t&1]: safe
        MQ32
        if (kt + 2 < nk) { VM(4); } else { VM(0); }   // t+1 landed
        wg_barrier();
    }

    // Epilogue (contiguous mapping: no unit interleave in this variant)
#pragma unroll
    for (int mi = 0; mi < 8; ++mi) {
#pragma unroll
        for (int ni = 0; ni < 4; ++ni) {
            const int col = n0 + wc * 64 + ni * 16 + r15;
            const float bc = bias[col];
#pragma unroll
            for (int j = 0; j < 4; ++j) {
                const int row = m0 + wr * 128 + mi * 16 + q * 4 + j;
                float v = acc[mi][ni][j] + bc;
                if (MODE == 1) {
                    float u = 1.5957691216057308f * (v + 0.044715f * v * v * v);
                    float s = 1.0f / (1.0f + __expf(-u));
                    outh[(size_t)row * N + col] = __float2bfloat16(v * s);
                } else {
                    outf[(size_t)row * N + col] =
                        x[(size_t)row * N + col] * g_res[row] + v * g_post[row];
                }
            }
        }
    }
}

// ===========================================================================
// VARIANT 0 (GEMM2 control): r9 kernel verbatim — 256x256, BK=64, 8-phase,
// unit-ring, VM(6) once per K-tile, LGKM0 before each MFMA cluster.
// ===========================================================================
#define RD_A(DST, REG)                                                            \
    _Pragma("unroll") for (int m = 0; m < 4; ++m) {                               \
        DST[m][0] = *(const bf16x8*)((REG) + baseA + m * 2048 + cb0);             \
        DST[m][1] = *(const bf16x8*)((REG) + baseA + m * 2048 + cb1);             \
    }
#define RD_B(DST, REG)                                                            \
    _Pragma("unroll") for (int n = 0; n < 2; ++n) {                               \
        DST[n][0] = *(const bf16x8*)((REG) + baseB + n * 2048 + cb0);             \
        DST[n][1] = *(const bf16x8*)((REG) + baseB + n * 2048 + cb1);             \
    }

#define MQ(AF, BF, MO, NO)                                                        \
    __builtin_amdgcn_s_setprio(1);                                                \
    _Pragma("unroll") for (int m = 0; m < 4; ++m)                                 \
    _Pragma("unroll") for (int n = 0; n < 2; ++n) {                               \
        acc[(MO) + m][(NO) + n] = __builtin_amdgcn_mfma_f32_16x16x32_bf16(        \
            AF[m][0], BF[n][0], acc[(MO) + m][(NO) + n], 0, 0, 0);                \
        acc[(MO) + m][(NO) + n] = __builtin_amdgcn_mfma_f32_16x16x32_bf16(        \
            AF[m][1], BF[n][1], acc[(MO) + m][(NO) + n], 0, 0, 0);                \
    }                                                                             \
    __builtin_amdgcn_s_setprio(0);

#define STG_A(t_, h_)                                                             \
    if ((t_) < nk) {                                                              \
        char* l_ = ldsA + (((t_) & 1) * 32768) + (h_) * 16384 + wave * 1024;      \
        async_copy16(Ab + aOff[0][h_] + (size_t)(t_) * 128, l_);                  \
        async_copy16(Ab + aOff[1][h_] + (size_t)(t_) * 128, l_ + 8192);           \
    }
#define STG_B(t_, h_)                                                             \
    if ((t_) < nk) {                                                              \
        char* l_ = ldsB + (((t_) & 1) * 32768) + (h_) * 16384 + wave * 1024;      \
        async_copy16(Bb + bOff[0][h_] + (size_t)(t_) * 128, l_);                  \
        async_copy16(Bb + bOff[1][h_] + (size_t)(t_) * 128, l_ + 8192);           \
    }

template <int MODE, int NB>
__global__ __launch_bounds__(512, 2) void gemm256(
    const __hip_bfloat16* __restrict__ A, const __hip_bfloat16* __restrict__ Bt,
    int M, int N, int K, const float* __restrict__ bias,
    __hip_bfloat16* __restrict__ outh, float* __restrict__ outf,
    const float* __restrict__ x, const float* __restrict__ g_res,
    const float* __restrict__ g_post) {
    __shared__ __align__(16) char ldsA[65536];
    __shared__ __align__(16) char ldsB[65536];

    const int wg = blockIdx.x;
    const int xcd = wg & 7;
    const int i = wg >> 3;
    const int nt = xcd * NB + (i % NB);
    const int mt = i / NB;
    const int m0 = mt * 256;
    const int n0 = nt * 256;

    const int tid = threadIdx.x;
    const int lane = tid & 63;
    const int wave = tid >> 6;            // 0..7
    const int wr = wave >> 2;             // 0..1 (M)
    const int wc = wave & 3;              // 0..3 (N)
    const int q = lane >> 4;              // 0..3
    const int rr = lane & 7;

    const uint32_t cb0 = (uint32_t)((q ^ rr) << 4);         // ks=0
    const uint32_t cb1 = (uint32_t)(((4 + q) ^ rr) << 4);   // ks=1
    const uint32_t baseA = (uint32_t)((wr * 64 + (lane & 15)) * 128);
    const uint32_t baseB = (uint32_t)((wc * 32 + (lane & 15)) * 128);

    const uint32_t scb = (uint32_t)((((lane & 7) ^ ((lane >> 3) & 7))) << 4);
    const int lr = lane >> 3;             // 0..7
    const size_t K2 = (size_t)K * 2;
    size_t aOff[2][2], bOff[2][2];
#pragma unroll
    for (int ii = 0; ii < 2; ++ii)
#pragma unroll
        for (int h = 0; h < 2; ++h) {
            int gA = m0 + wave * 8 + lr + ii * 128 + h * 64;
            int gB = n0 + ((wave >> 2) + 2 * ii) * 64 + h * 32 + (wave & 3) * 8 + lr;
            aOff[ii][h] = (size_t)gA * K2 + scb;
            bOff[ii][h] = (size_t)gB * K2 + scb;
        }
    const char* Ab = (const char*)A;
    const char* Bb = (const char*)Bt;

    f32x4 acc[8][4];
#pragma unroll
    for (int m = 0; m < 8; ++m)
#pragma unroll
        for (int n = 0; n < 4; ++n) acc[m][n] = (f32x4){0.f, 0.f, 0.f, 0.f};

    const int nk = K / 64;

    STG_A(0, 0); STG_B(0, 0); STG_B(0, 1); STG_A(0, 1);
    STG_A(1, 0); STG_B(1, 0); STG_A(1, 1);
    VM(6);
    wg_barrier();

    bf16x8 a0[4][2], a1[4][2];
    bf16x8 b0[2][2], b1[2][2];

    for (int kt = 0; kt < nk; ++kt) {
        const int c = kt & 1;
        const char* Ac = ldsA + c * 32768;
        const char* Bc = ldsB + c * 32768;
        // ---- P1
        RD_A(a0, Ac)
        RD_B(b0, Bc)
        STG_B(kt + 1, 1)
        LGKM8;
        wg_barrier();
        LGKM0;
        MQ(a0, b0, 0, 0)
        wg_barrier();
        // ---- P2
        RD_B(b1, Bc + 16384)
        STG_A(kt + 2, 0)
        wg_barrier();
        LGKM0;
        MQ(a0, b1, 0, 2)
        wg_barrier();
        // ---- P3
        RD_A(a1, Ac + 16384)
        STG_B(kt + 2, 0)
        wg_barrier();
        LGKM0;
        MQ(a1, b0, 4, 0)
        wg_barrier();
        // ---- P4
        STG_A(kt + 2, 1)
        if (kt + 2 < nk) { VM(6); } else { VM(0); }
        wg_barrier();
        MQ(a1, b1, 4, 2)
        wg_barrier();
    }

#pragma unroll
    for (int mi = 0; mi < 8; ++mi) {
#pragma unroll
        for (int ni = 0; ni < 4; ++ni) {
            const int col = n0 + wc * 64 + (ni >> 1) * 32 + (ni & 1) * 16 + (lane & 15);
            const float bc = bias[col];
#pragma unroll
            for (int j = 0; j < 4; ++j) {
                const int row = m0 + wr * 128 + (mi >> 2) * 64 + (mi & 3) * 16 + q * 4 + j;
                float v = acc[mi][ni][j] + bc;
                if (MODE == 1) {
                    float u = 1.5957691216057308f * (v + 0.044715f * v * v * v);
                    float s = 1.0f / (1.0f + __expf(-u));
                    outh[(size_t)row * N + col] = __float2bfloat16(v * s);
                } else {
                    outf[(size_t)row * N + col] =
                        x[(size_t)row * N + col] * g_res[row] + v * g_post[row];
                }
            }
        }
    }
}

// ---------------------------------------------------------------------------
// Workspace layout (~235.2 MB): W1T, W2T, Abuf, Hbuf, Wfold, gres, gpost
// ---------------------------------------------------------------------------
extern "C" void kernel_launch(void* const* d_in, const int* in_sizes, int n_in,
                              void* d_out, int out_size, void* d_ws, size_t ws_size,
                              hipStream_t stream) {
    const float* x          = (const float*)d_in[0];
    const float* phi_pre_w  = (const float*)d_in[1];
    const float* phi_pre_b  = (const float*)d_in[2];
    const float* phi_post_w = (const float*)d_in[3];
    const float* phi_post_b = (const float*)d_in[4];
    const float* phi_res_w  = (const float*)d_in[5];
    const float* phi_res_b  = (const float*)d_in[6];
    const float* alpha_pre  = (const float*)d_in[7];
    const float* alpha_post = (const float*)d_in[8];
    const float* alpha_res  = (const float*)d_in[9];
    const float* b_pre      = (const float*)d_in[10];
    const float* b_post     = (const float*)d_in[11];
    const float* b_res      = (const float*)d_in[12];
    const float* W1         = (const float*)d_in[13];
    const float* b1         = (const float*)d_in[14];
    const float* W2         = (const float*)d_in[15];
    const float* b2         = (const float*)d_in[16];
    float* out = (float*)d_out;

    char* ws = (char*)d_ws;
    __hip_bfloat16* W1T  = (__hip_bfloat16*)ws;                      // [DFF][DIM]
    __hip_bfloat16* W2T  = W1T + (size_t)DFF * DIM;                  // [DIM][DFF]
    __hip_bfloat16* Abuf = W2T + (size_t)DIM * DFF;                  // [NROWS][DIM]
    __hip_bfloat16* Hbuf = Abuf + (size_t)NROWS * DIM;               // [NROWS][DFF]
    float* Wfold = (float*)(Hbuf + (size_t)NROWS * DFF);             // [24][DIM]
    float* gres  = Wfold + NFOLD * DIM;
    float* gpost = gres + NROWS;

    fold_kernel<<<(NFOLD * DIM + 255) / 256, 256, 0, stream>>>(phi_pre_w, phi_post_w,
                                                               phi_res_w, Wfold);
    transpose_to_bf16<<<dim3(DFF / 32, DIM / 32), 256, 0, stream>>>(W1, W1T, DIM, DFF);
    transpose_to_bf16<<<dim3(DIM / 32, DFF / 32), 256, 0, stream>>>(W2, W2T, DFF, DIM);
    gating_kernel<<<NROWS / 8, 512, 0, stream>>>(x, Wfold, phi_pre_b, phi_post_b, phi_res_b,
                                                 alpha_pre, alpha_post, alpha_res,
                                                 b_pre, b_post, b_res, Abuf, gres, gpost);
    // GEMM1 (VARIANT: BK32, 2 blocks/CU): grid 32x32=1024, NB=4
    gemm256_bk32<1, 4><<<1024, 512, 0, stream>>>(
        Abuf, W1T, NROWS, DFF, DIM, b1, Hbuf, nullptr, nullptr, nullptr, nullptr);
    // GEMM2 (CONTROL: r9 kernel): grid 32x8=256, NB=1
    gemm256<2, 1><<<256, 512, 0, stream>>>(
        Hbuf, W2T, NROWS, DIM, DFF, b2, nullptr, out, x, gres, gpost);
}

// Round 15
// 728.377 us; speedup vs baseline: 4.6211x; 4.6211x over previous
//
#include <hip/hip_runtime.h>
#include <hip/hip_bf16.h>
#include <cstdint>
#include <cstddef>

// Problem constants (B=4, T=2048, DIM=2048, S=4, DFF=8192)
#define DIM   2048
#define DFF   8192
#define NROWS 8192   // B*T
#define NFOLD 24     // 4 (pre) + 4 (post) + 16 (res)

typedef float f32x4 __attribute__((ext_vector_type(4)));
typedef __bf16 bf16x8 __attribute__((ext_vector_type(8)));

__device__ __forceinline__ float sigmoidf_(float v) { return 1.0f / (1.0f + expf(-v)); }

__device__ __forceinline__ unsigned short f2bf(float v) {
    union { __hip_bfloat16 h; unsigned short u; } cv;
    cv.h = __float2bfloat16(v);
    return cv.u;
}

__device__ __forceinline__ void async_copy16(const void* g, void* l) {
    __builtin_amdgcn_global_load_lds((const __attribute__((address_space(1))) void*)g,
                                     (__attribute__((address_space(3))) void*)l, 16, 0, 0);
}

// Raw workgroup barrier WITHOUT waitcnt drain (keeps global_load_lds in flight).
__device__ __forceinline__ void wg_barrier() {
    asm volatile("" ::: "memory");
    __builtin_amdgcn_s_barrier();
    asm volatile("" ::: "memory");
}

#define VM(n)   asm volatile("s_waitcnt vmcnt(" #n ")" ::: "memory")
#define LGKM(n) asm volatile("s_waitcnt lgkmcnt(" #n ")" ::: "memory")
#define LGKM0   asm volatile("s_waitcnt lgkmcnt(0)" ::: "memory")
// ROUND 15: read-one-phase-AHEAD + counted lgkm AFTER bar1 (m201's "4 or 8
// reads/phase" fingerprint). Each phase's ds_reads feed the NEXT phase's
// MFMA; the post-bar1 lgkmcnt(N) drains only the PREVIOUS phase's reads
// (already retired under the last MFMA cluster), so this phase's reads drain
// on the LDS port UNDER this phase's MFMA cluster. r14's BK32 attempt was
// invalidated by launch_bounds(512,4) -> 64-VGPR cap -> acc spill (5.3 GB
// FETCH); occupancy is not available at 256^2 tile.

// ---------------------------------------------------------------------------
// Fold phi weights: Wfold[r][d] = sum_{j<4} src[r][j*DIM + d], r in [0,24)
// ---------------------------------------------------------------------------
__global__ __launch_bounds__(256) void fold_kernel(const float* __restrict__ pre_w,
                                                   const float* __restrict__ post_w,
                                                   const float* __restrict__ res_w,
                                                   float* __restrict__ Wfold) {
    int idx = blockIdx.x * 256 + threadIdx.x;
    if (idx >= NFOLD * DIM) return;
    int r = idx >> 11;          // /DIM
    int d = idx & (DIM - 1);
    const float* src;
    if (r < 4)      src = pre_w  + (size_t)r * (4 * DIM);
    else if (r < 8) src = post_w + (size_t)(r - 4) * (4 * DIM);
    else            src = res_w  + (size_t)(r - 8) * (4 * DIM);
    Wfold[idx] = src[d] + src[DIM + d] + src[2 * DIM + d] + src[3 * DIM + d];
}

// ---------------------------------------------------------------------------
// Transpose f32 [R][C] -> bf16 [C][R]
// ---------------------------------------------------------------------------
__global__ __launch_bounds__(256) void transpose_to_bf16(const float* __restrict__ in,
                                                         __hip_bfloat16* __restrict__ out,
                                                         int R, int C) {
    __shared__ float tile[32][33];
    int bx = blockIdx.x, by = blockIdx.y;
    int tx = threadIdx.x & 31, ty0 = threadIdx.x >> 5;
#pragma unroll
    for (int i = 0; i < 4; i++) {
        int ty = ty0 + i * 8;
        tile[ty][tx] = in[(size_t)(by * 32 + ty) * C + bx * 32 + tx];
    }
    __syncthreads();
#pragma unroll
    for (int i = 0; i < 4; i++) {
        int ty = ty0 + i * 8;
        out[(size_t)(bx * 32 + ty) * R + by * 32 + tx] = __float2bfloat16(tile[tx][ty]);
    }
}

// ---------------------------------------------------------------------------
// Gating: wave-per-row, 8 rows per block (512 threads).
// ---------------------------------------------------------------------------
__global__ __launch_bounds__(512) void gating_kernel(
    const float* __restrict__ x, const float* __restrict__ Wfold,
    const float* __restrict__ phi_pre_b, const float* __restrict__ phi_post_b,
    const float* __restrict__ phi_res_b,
    const float* __restrict__ alpha_pre, const float* __restrict__ alpha_post,
    const float* __restrict__ alpha_res,
    const float* __restrict__ b_pre, const float* __restrict__ b_post,
    const float* __restrict__ b_res,
    __hip_bfloat16* __restrict__ Abuf,
    float* __restrict__ g_res_arr, float* __restrict__ g_post_arr) {
    const int tid = threadIdx.x;
    const int lane = tid & 63, wave = tid >> 6;
    const int row = blockIdx.x * 8 + wave;

    const float4* x4 = (const float4*)x + (size_t)row * 512;
    const float4* w4 = (const float4*)Wfold;

    float4 xv[8];
#pragma unroll
    for (int j = 0; j < 8; j++) xv[j] = x4[j * 64 + lane];

    float p[25];
    p[24] = 0.f;
#pragma unroll
    for (int j = 0; j < 8; j++)
        p[24] += xv[j].x * xv[j].x + xv[j].y * xv[j].y + xv[j].z * xv[j].z + xv[j].w * xv[j].w;

    for (int r = 0; r < NFOLD; r++) {
        float acc = 0.f;
#pragma unroll
        for (int j = 0; j < 8; j++) {
            float4 wv = w4[r * 512 + j * 64 + lane];
            acc += xv[j].x * wv.x + xv[j].y * wv.y + xv[j].z * wv.z + xv[j].w * wv.w;
        }
        p[r] = acc;
    }

#pragma unroll
    for (int r = 0; r < 25; r++) {
        float v = p[r];
#pragma unroll
        for (int off = 1; off < 64; off <<= 1) v += __shfl_xor(v, off, 64);
        p[r] = v;
    }

    const float rms = rsqrtf(p[24] / (float)DIM + 1.1920928955078125e-07f);
    const float ap = alpha_pre[0], aq = alpha_post[0], ar = alpha_res[0];
    float gpre = 0.f, gpost = 0.f;
#pragma unroll
    for (int s = 0; s < 4; s++) {
        gpre  += sigmoidf_(ap * (rms * p[s]     + phi_pre_b[s])  + b_pre[s]);
        gpost += 2.0f * sigmoidf_(aq * (rms * p[4 + s] + phi_post_b[s]) + b_post[s]);
    }
    float Mm[4][4];
#pragma unroll
    for (int i = 0; i < 4; i++)
#pragma unroll
        for (int j = 0; j < 4; j++) {
            int k = i * 4 + j;
            Mm[i][j] = expf(ar * (rms * p[8 + k] + phi_res_b[k]) + b_res[k]);
        }
    for (int it = 0; it < 10; ++it) {
#pragma unroll
        for (int i = 0; i < 4; i++) {
            float rs = 1.0f / (Mm[i][0] + Mm[i][1] + Mm[i][2] + Mm[i][3]);
#pragma unroll
            for (int j = 0; j < 4; j++) Mm[i][j] *= rs;
        }
#pragma unroll
        for (int j = 0; j < 4; j++) {
            float cs = 1.0f / (Mm[0][j] + Mm[1][j] + Mm[2][j] + Mm[3][j]);
#pragma unroll
            for (int i = 0; i < 4; i++) Mm[i][j] *= cs;
        }
    }
    float gres = 0.f;
#pragma unroll
    for (int i = 0; i < 4; i++)
#pragma unroll
        for (int j = 0; j < 4; j++) gres += Mm[i][j];

    __hip_bfloat16* arow = Abuf + (size_t)row * DIM;
#pragma unroll
    for (int j = 0; j < 8; j++) {
        ushort4 u;
        u.x = f2bf(xv[j].x * gpre); u.y = f2bf(xv[j].y * gpre);
        u.z = f2bf(xv[j].z * gpre); u.w = f2bf(xv[j].w * gpre);
        *reinterpret_cast<ushort4*>(arow + (j * 64 + lane) * 4) = u;
    }
    if (lane == 0) {
        g_res_arr[row]  = gres;
        g_post_arr[row] = gpost;
    }
}

// ---------------------------------------------------------------------------
// 256x256 bf16 GEMM — READ-AHEAD 8-phase (2 bar/phase), counted lgkm AFTER
// bar1, two counted vmcnts per K-tile.
//   C[M][N] = A[M][K] @ Bt[N][K]^T; 8 waves (2M x 4N); per-wave out 128x64;
//   BK=64; LDS 128 KiB = 2 parities x {A0,A1,B0,B1} 16 KB units.
// Units: A0: rows {0-63,128-191} [a0] | A1: rows {64-127,192-255} [a1]
//        B0: cols {0-31,64-95,128-159,192-223} [b0] | B1: +32 [b1]
// Unit region [128 rows][128 B], byte col ^ ((row&7)<<4); global_load_lds
// writes linearly, inverse XOR pre-applied on the per-lane global source.
//
// Phase = { ds_reads (for NEXT phase's MFMA); 1 stage; [VM]; bar1;
//           LGKM(n)=own-read-count (drains only PREVIOUS phase's reads);
//           setprio1; 16 MFMA; setprio0; bar2 }
//   P1: rd b1(t)  [4]; stg B1(t+1);         LGKM(4); MFMA(a0,b0)
//   P2: rd a1(t)  [8]; stg A0(t+2); VM(4);  LGKM(8); MFMA(a0,b1)
//   P3: rd a0(t+1)[8]; stg B0(t+2);         LGKM(8); MFMA(a1,b0)
//   P4: rd b0(t+1)[4]; stg A1(t+2); VM(6);  LGKM(4); MFMA(a1,b1)
// This phase's reads drain on the LDS port UNDER this phase's MFMA; the
// LGKM(n) only waits for reads issued one phase earlier (already retired).
// lgkm FIFO (per wave, in-order DS): P1 pre-wait outstanding = b0'[4]+b1[4]
//   -> LGKM(4) drains b0'(=b0(t), needed now). P2: b1[4]+a1[8] -> LGKM(8)
//   drains b1. P3: a1[8]+a0'[8] -> LGKM(8) drains a1. P4: a0'[8]+b0'[4] ->
//   LGKM(4) drains a0'.
// vmcnt FIFO (loads; 2/stage): VM(4)@P2(t) keeps {B1(t+1),A0(t+2)}, lands
//   {A0,B0,A1}(t+1) before P3/P4 read them. VM(6)@P4(t) keeps {A0,B0,A1}
//   (t+2), lands B1(t+1) before P1(t+1) reads it.
// WAR (region: last read -> lgkm pin -> overwrite issue, all >=1 barrier
//   apart): A0(t) rd P3(t-1)/pin P4(t-1)/ovw P2(t); B0(t) rd P4(t-1)/pin
//   P1(t)/ovw P3(t); B1(t) rd P1(t)/pin P2(t)/ovw P1(t+1); A1(t) rd P2(t)/
//   pin P3(t)/ovw P4(t).
// Prologue: stage t0{A0,B0,B1,A1}+t1{A0,B0,A1}; VM(6) lands tile0, leaves
//   {A0,B0,A1}(1) in flight (steady invariant); pre-read a0(0),b0(0); pin.
// Tail (kt >= nk-2): LGKM0 + VM(0); reads/stages self-guarded.
// ---------------------------------------------------------------------------
#define RD_A(DST, REG)                                                            \
    _Pragma("unroll") for (int m = 0; m < 4; ++m) {                               \
        DST[m][0] = *(const bf16x8*)((REG) + baseA + m * 2048 + cb0);             \
        DST[m][1] = *(const bf16x8*)((REG) + baseA + m * 2048 + cb1);             \
    }
#define RD_B(DST, REG)                                                            \
    _Pragma("unroll") for (int n = 0; n < 2; ++n) {                               \
        DST[n][0] = *(const bf16x8*)((REG) + baseB + n * 2048 + cb0);             \
        DST[n][1] = *(const bf16x8*)((REG) + baseB + n * 2048 + cb1);             \
    }

#define MQ(AF, BF, MO, NO)                                                        \
    __builtin_amdgcn_s_setprio(1);                                                \
    _Pragma("unroll") for (int m = 0; m < 4; ++m)                                 \
    _Pragma("unroll") for (int n = 0; n < 2; ++n) {                               \
        acc[(MO) + m][(NO) + n] = __builtin_amdgcn_mfma_f32_16x16x32_bf16(        \
            AF[m][0], BF[n][0], acc[(MO) + m][(NO) + n], 0, 0, 0);                \
        acc[(MO) + m][(NO) + n] = __builtin_amdgcn_mfma_f32_16x16x32_bf16(        \
            AF[m][1], BF[n][1], acc[(MO) + m][(NO) + n], 0, 0, 0);                \
    }                                                                             \
    __builtin_amdgcn_s_setprio(0);

#define STG_A(t_, h_)                                                             \
    if ((t_) < nk) {                                                              \
        char* l_ = ldsA + (((t_) & 1) * 32768) + (h_) * 16384 + wave * 1024;      \
        async_copy16(Ab + aOff[0][h_] + (size_t)(t_) * 128, l_);                  \
        async_copy16(Ab + aOff[1][h_] + (size_t)(t_) * 128, l_ + 8192);           \
    }
#define STG_B(t_, h_)                                                             \
    if ((t_) < nk) {                                                              \
        char* l_ = ldsB + (((t_) & 1) * 32768) + (h_) * 16384 + wave * 1024;      \
        async_copy16(Bb + bOff[0][h_] + (size_t)(t_) * 128, l_);                  \
        async_copy16(Bb + bOff[1][h_] + (size_t)(t_) * 128, l_ + 8192);           \
    }

template <int MODE, int NB>
__global__ __launch_bounds__(512, 2) void gemm256(
    const __hip_bfloat16* __restrict__ A, const __hip_bfloat16* __restrict__ Bt,
    int M, int N, int K, const float* __restrict__ bias,
    __hip_bfloat16* __restrict__ outh, float* __restrict__ outf,
    const float* __restrict__ x, const float* __restrict__ g_res,
    const float* __restrict__ g_post) {
    __shared__ __align__(16) char ldsA[65536];
    __shared__ __align__(16) char ldsB[65536];

    // XCD band swizzle: each XCD owns an NB-wide column band of tiles.
    const int wg = blockIdx.x;
    const int xcd = wg & 7;
    const int i = wg >> 3;
    const int nt = xcd * NB + (i % NB);
    const int mt = i / NB;
    const int m0 = mt * 256;
    const int n0 = nt * 256;

    const int tid = threadIdx.x;
    const int lane = tid & 63;
    const int wave = tid >> 6;            // 0..7
    const int wr = wave >> 2;             // 0..1 (M)
    const int wc = wave & 3;              // 0..3 (N)
    const int q = lane >> 4;              // 0..3
    const int rr = lane & 7;

    // ds_read addressing (bytes within a 16 KB unit region)
    const uint32_t cb0 = (uint32_t)((q ^ rr) << 4);         // ks=0
    const uint32_t cb1 = (uint32_t)(((4 + q) ^ rr) << 4);   // ks=1
    const uint32_t baseA = (uint32_t)((wr * 64 + (lane & 15)) * 128);
    const uint32_t baseB = (uint32_t)((wc * 32 + (lane & 15)) * 128);

    // staging source addressing
    const uint32_t scb = (uint32_t)((((lane & 7) ^ ((lane >> 3) & 7))) << 4);
    const int lr = lane >> 3;             // 0..7
    const size_t K2 = (size_t)K * 2;
    size_t aOff[2][2], bOff[2][2];
#pragma unroll
    for (int ii = 0; ii < 2; ++ii)
#pragma unroll
        for (int h = 0; h < 2; ++h) {
            int gA = m0 + wave * 8 + lr + ii * 128 + h * 64;
            int gB = n0 + ((wave >> 2) + 2 * ii) * 64 + h * 32 + (wave & 3) * 8 + lr;
            aOff[ii][h] = (size_t)gA * K2 + scb;
            bOff[ii][h] = (size_t)gB * K2 + scb;
        }
    const char* Ab = (const char*)A;
    const char* Bb = (const char*)Bt;

    f32x4 acc[8][4];
#pragma unroll
    for (int m = 0; m < 8; ++m)
#pragma unroll
        for (int n = 0; n < 4; ++n) acc[m][n] = (f32x4){0.f, 0.f, 0.f, 0.f};

    const int nk = K / 64;

    // Prologue: tile0 {A0,B0,B1,A1} + tile1 {A0,B0,A1}; VM(6) lands tile0
    // and leaves {A0,B0,A1}(1) in flight (the steady-state invariant).
    STG_A(0, 0); STG_B(0, 0); STG_B(0, 1); STG_A(0, 1);
    STG_A(1, 0); STG_B(1, 0); STG_A(1, 1);
    VM(6);
    wg_barrier();

    bf16x8 a0[4][2], a1[4][2];
    bf16x8 b0[2][2], b1[2][2];
    RD_A(a0, ldsA)
    RD_B(b0, ldsB)
    LGKM0;          // pin pre-reads before any overwrite (r6 lesson)
    wg_barrier();

    for (int kt = 0; kt < nk; ++kt) {
        const char* Ac = ldsA + (kt & 1) * 32768;
        const char* Bc = ldsB + (kt & 1) * 32768;
        const char* An = ldsA + ((kt + 1) & 1) * 32768;
        const char* Bn = ldsB + ((kt + 1) & 1) * 32768;
        const bool steady = (kt < nk - 2);
        // ---- P1: rd b1(t); stg B1(t+1); || MFMA(a0,b0)
        RD_B(b1, Bc + 16384)
        STG_B(kt + 1, 1)
        wg_barrier();
        if (steady) { LGKM(4); } else { LGKM0; }
        MQ(a0, b0, 0, 0)
        wg_barrier();
        // ---- P2: rd a1(t); stg A0(t+2); VM(4) || MFMA(a0,b1)
        RD_A(a1, Ac + 16384)
        STG_A(kt + 2, 0)
        if (steady) { VM(4); } else { VM(0); }
        wg_barrier();
        if (steady) { LGKM(8); } else { LGKM0; }
        MQ(a0, b1, 0, 2)
        wg_barrier();
        // ---- P3: rd a0(t+1); stg B0(t+2); || MFMA(a1,b0)
        if (kt + 1 < nk) { RD_A(a0, An) }
        STG_B(kt + 2, 0)
        wg_barrier();
        if (steady) { LGKM(8); } else { LGKM0; }
        MQ(a1, b0, 4, 0)
        wg_barrier();
        // ---- P4: rd b0(t+1); stg A1(t+2); VM(6) || MFMA(a1,b1)
        if (kt + 1 < nk) { RD_B(b0, Bn) }
        STG_A(kt + 2, 1)
        if (steady) { VM(6); } else { VM(0); }
        wg_barrier();
        if (steady) { LGKM(4); } else { LGKM0; }
        MQ(a1, b1, 4, 2)
        wg_barrier();
    }

    // Epilogue. Row/col mapping follows the interleaved unit layout:
    //   rows:  m0 + wr*128 + (mi>>2)*64 + (mi&3)*16 + q*4 + j
    //   cols:  n0 + wc*64  + (ni>>1)*32 + (ni&1)*16 + (lane&15)
#pragma unroll
    for (int mi = 0; mi < 8; ++mi) {
#pragma unroll
        for (int ni = 0; ni < 4; ++ni) {
            const int col = n0 + wc * 64 + (ni >> 1) * 32 + (ni & 1) * 16 + (lane & 15);
            const float bc = bias[col];
#pragma unroll
            for (int j = 0; j < 4; ++j) {
                const int row = m0 + wr * 128 + (mi >> 2) * 64 + (mi & 3) * 16 + q * 4 + j;
                float v = acc[mi][ni][j] + bc;
                if (MODE == 1) {
                    // tanh-form GELU via fast exp (max dev vs erf-GELU ~3e-4)
                    float u = 1.5957691216057308f * (v + 0.044715f * v * v * v);
                    float s = 1.0f / (1.0f + __expf(-u));
                    outh[(size_t)row * N + col] = __float2bfloat16(v * s);
                } else {
                    outf[(size_t)row * N + col] =
                        x[(size_t)row * N + col] * g_res[row] + v * g_post[row];
                }
            }
        }
    }
}

// ---------------------------------------------------------------------------
// Workspace layout (~235.2 MB): W1T, W2T, Abuf, Hbuf, Wfold, gres, gpost
// ---------------------------------------------------------------------------
extern "C" void kernel_launch(void* const* d_in, const int* in_sizes, int n_in,
                              void* d_out, int out_size, void* d_ws, size_t ws_size,
                              hipStream_t stream) {
    const float* x          = (const float*)d_in[0];
    const float* phi_pre_w  = (const float*)d_in[1];
    const float* phi_pre_b  = (const float*)d_in[2];
    const float* phi_post_w = (const float*)d_in[3];
    const float* phi_post_b = (const float*)d_in[4];
    const float* phi_res_w  = (const float*)d_in[5];
    const float* phi_res_b  = (const float*)d_in[6];
    const float* alpha_pre  = (const float*)d_in[7];
    const float* alpha_post = (const float*)d_in[8];
    const float* alpha_res  = (const float*)d_in[9];
    const float* b_pre      = (const float*)d_in[10];
    const float* b_post     = (const float*)d_in[11];
    const float* b_res      = (const float*)d_in[12];
    const float* W1         = (const float*)d_in[13];
    const float* b1         = (const float*)d_in[14];
    const float* W2         = (const float*)d_in[15];
    const float* b2         = (const float*)d_in[16];
    float* out = (float*)d_out;

    char* ws = (char*)d_ws;
    __hip_bfloat16* W1T  = (__hip_bfloat16*)ws;                      // [DFF][DIM]
    __hip_bfloat16* W2T  = W1T + (size_t)DFF * DIM;                  // [DIM][DFF]
    __hip_bfloat16* Abuf = W2T + (size_t)DIM * DFF;                  // [NROWS][DIM]
    __hip_bfloat16* Hbuf = Abuf + (size_t)NROWS * DIM;               // [NROWS][DFF]
    float* Wfold = (float*)(Hbuf + (size_t)NROWS * DFF);             // [24][DIM]
    float* gres  = Wfold + NFOLD * DIM;
    float* gpost = gres + NROWS;

    fold_kernel<<<(NFOLD * DIM + 255) / 256, 256, 0, stream>>>(phi_pre_w, phi_post_w,
                                                               phi_res_w, Wfold);
    transpose_to_bf16<<<dim3(DFF / 32, DIM / 32), 256, 0, stream>>>(W1, W1T, DIM, DFF);
    transpose_to_bf16<<<dim3(DIM / 32, DFF / 32), 256, 0, stream>>>(W2, W2T, DFF, DIM);
    gating_kernel<<<NROWS / 8, 512, 0, stream>>>(x, Wfold, phi_pre_b, phi_post_b, phi_res_b,
                                                 alpha_pre, alpha_post, alpha_res,
                                                 b_pre, b_post, b_res, Abuf, gres, gpost);
    // GEMM1: [8192 x 2048] @ W1 -> gelu -> Hbuf [8192 x 8192]; grid 32x32=1024, NB=4
    gemm256<1, 4><<<1024, 512, 0, stream>>>(
        Abuf, W1T, NROWS, DFF, DIM, b1, Hbuf, nullptr, nullptr, nullptr, nullptr);
    // GEMM2: [8192 x 8192] @ W2 -> out [8192 x 2048]; grid 32x8=256, NB=1
    gemm256<2, 1><<<256, 512, 0, stream>>>(
        Hbuf, W2T, NROWS, DIM, DFF, b2, nullptr, out, x, gres, gpost);
}

// Round 16
// 640.124 us; speedup vs baseline: 5.2582x; 1.1379x over previous
//
#include <hip/hip_runtime.h>
#include <hip/hip_bf16.h>
#include <cstdint>
#include <cstddef>

// Problem constants (B=4, T=2048, DIM=2048, S=4, DFF=8192)
#define DIM   2048
#define DFF   8192
#define NROWS 8192   // B*T
#define NFOLD 24     // 4 (pre) + 4 (post) + 16 (res)

typedef float f32x4 __attribute__((ext_vector_type(4)));
typedef __bf16 bf16x8 __attribute__((ext_vector_type(8)));

__device__ __forceinline__ float sigmoidf_(float v) { return 1.0f / (1.0f + expf(-v)); }

__device__ __forceinline__ unsigned short f2bf(float v) {
    union { __hip_bfloat16 h; unsigned short u; } cv;
    cv.h = __float2bfloat16(v);
    return cv.u;
}

__device__ __forceinline__ void async_copy16(const void* g, void* l) {
    __builtin_amdgcn_global_load_lds((const __attribute__((address_space(1))) void*)g,
                                     (__attribute__((address_space(3))) void*)l, 16, 0, 0);
}

// Raw workgroup barrier WITHOUT waitcnt drain (keeps global_load_lds in flight).
__device__ __forceinline__ void wg_barrier() {
    asm volatile("" ::: "memory");
    __builtin_amdgcn_s_barrier();
    asm volatile("" ::: "memory");
}

#define VM(n)  asm volatile("s_waitcnt vmcnt(" #n ")" ::: "memory")
#define LGKM0  asm volatile("s_waitcnt lgkmcnt(0)" ::: "memory")
#define LGKM8  asm volatile("s_waitcnt lgkmcnt(8)" ::: "memory")
// ROUND 16: r8/r9 schedule with the POST-MFMA barrier removed (4 barriers/
// tile instead of 8). The trailing barrier is provably redundant: a wave
// stages unit U only after crossing the NEXT phase's barrier, and every
// other wave reaches that barrier only after its LGKM0 < MFMA — reads of U
// pinned complete. Removing it lets waves skew within each interval: fast
// waves issue next reads/stage (LDS port) while slow waves are still in
// MFMA (matrix pipes) — the port/MFMA overlap the 8 lockstep variants
// (r7-r15, all 295-360us) could not express.

// ---------------------------------------------------------------------------
// Fold phi weights: Wfold[r][d] = sum_{j<4} src[r][j*DIM + d], r in [0,24)
// ---------------------------------------------------------------------------
__global__ __launch_bounds__(256) void fold_kernel(const float* __restrict__ pre_w,
                                                   const float* __restrict__ post_w,
                                                   const float* __restrict__ res_w,
                                                   float* __restrict__ Wfold) {
    int idx = blockIdx.x * 256 + threadIdx.x;
    if (idx >= NFOLD * DIM) return;
    int r = idx >> 11;          // /DIM
    int d = idx & (DIM - 1);
    const float* src;
    if (r < 4)      src = pre_w  + (size_t)r * (4 * DIM);
    else if (r < 8) src = post_w + (size_t)(r - 4) * (4 * DIM);
    else            src = res_w  + (size_t)(r - 8) * (4 * DIM);
    Wfold[idx] = src[d] + src[DIM + d] + src[2 * DIM + d] + src[3 * DIM + d];
}

// ---------------------------------------------------------------------------
// Transpose f32 [R][C] -> bf16 [C][R]
// ---------------------------------------------------------------------------
__global__ __launch_bounds__(256) void transpose_to_bf16(const float* __restrict__ in,
                                                         __hip_bfloat16* __restrict__ out,
                                                         int R, int C) {
    __shared__ float tile[32][33];
    int bx = blockIdx.x, by = blockIdx.y;
    int tx = threadIdx.x & 31, ty0 = threadIdx.x >> 5;
#pragma unroll
    for (int i = 0; i < 4; i++) {
        int ty = ty0 + i * 8;
        tile[ty][tx] = in[(size_t)(by * 32 + ty) * C + bx * 32 + tx];
    }
    __syncthreads();
#pragma unroll
    for (int i = 0; i < 4; i++) {
        int ty = ty0 + i * 8;
        out[(size_t)(bx * 32 + ty) * R + by * 32 + tx] = __float2bfloat16(tile[tx][ty]);
    }
}

// ---------------------------------------------------------------------------
// Gating: wave-per-row, 8 rows per block (512 threads).
// ---------------------------------------------------------------------------
__global__ __launch_bounds__(512) void gating_kernel(
    const float* __restrict__ x, const float* __restrict__ Wfold,
    const float* __restrict__ phi_pre_b, const float* __restrict__ phi_post_b,
    const float* __restrict__ phi_res_b,
    const float* __restrict__ alpha_pre, const float* __restrict__ alpha_post,
    const float* __restrict__ alpha_res,
    const float* __restrict__ b_pre, const float* __restrict__ b_post,
    const float* __restrict__ b_res,
    __hip_bfloat16* __restrict__ Abuf,
    float* __restrict__ g_res_arr, float* __restrict__ g_post_arr) {
    const int tid = threadIdx.x;
    const int lane = tid & 63, wave = tid >> 6;
    const int row = blockIdx.x * 8 + wave;

    const float4* x4 = (const float4*)x + (size_t)row * 512;
    const float4* w4 = (const float4*)Wfold;

    float4 xv[8];
#pragma unroll
    for (int j = 0; j < 8; j++) xv[j] = x4[j * 64 + lane];

    float p[25];
    p[24] = 0.f;
#pragma unroll
    for (int j = 0; j < 8; j++)
        p[24] += xv[j].x * xv[j].x + xv[j].y * xv[j].y + xv[j].z * xv[j].z + xv[j].w * xv[j].w;

    for (int r = 0; r < NFOLD; r++) {
        float acc = 0.f;
#pragma unroll
        for (int j = 0; j < 8; j++) {
            float4 wv = w4[r * 512 + j * 64 + lane];
            acc += xv[j].x * wv.x + xv[j].y * wv.y + xv[j].z * wv.z + xv[j].w * wv.w;
        }
        p[r] = acc;
    }

#pragma unroll
    for (int r = 0; r < 25; r++) {
        float v = p[r];
#pragma unroll
        for (int off = 1; off < 64; off <<= 1) v += __shfl_xor(v, off, 64);
        p[r] = v;
    }

    const float rms = rsqrtf(p[24] / (float)DIM + 1.1920928955078125e-07f);
    const float ap = alpha_pre[0], aq = alpha_post[0], ar = alpha_res[0];
    float gpre = 0.f, gpost = 0.f;
#pragma unroll
    for (int s = 0; s < 4; s++) {
        gpre  += sigmoidf_(ap * (rms * p[s]     + phi_pre_b[s])  + b_pre[s]);
        gpost += 2.0f * sigmoidf_(aq * (rms * p[4 + s] + phi_post_b[s]) + b_post[s]);
    }
    float Mm[4][4];
#pragma unroll
    for (int i = 0; i < 4; i++)
#pragma unroll
        for (int j = 0; j < 4; j++) {
            int k = i * 4 + j;
            Mm[i][j] = expf(ar * (rms * p[8 + k] + phi_res_b[k]) + b_res[k]);
        }
    for (int it = 0; it < 10; ++it) {
#pragma unroll
        for (int i = 0; i < 4; i++) {
            float rs = 1.0f / (Mm[i][0] + Mm[i][1] + Mm[i][2] + Mm[i][3]);
#pragma unroll
            for (int j = 0; j < 4; j++) Mm[i][j] *= rs;
        }
#pragma unroll
        for (int j = 0; j < 4; j++) {
            float cs = 1.0f / (Mm[0][j] + Mm[1][j] + Mm[2][j] + Mm[3][j]);
#pragma unroll
            for (int i = 0; i < 4; i++) Mm[i][j] *= cs;
        }
    }
    float gres = 0.f;
#pragma unroll
    for (int i = 0; i < 4; i++)
#pragma unroll
        for (int j = 0; j < 4; j++) gres += Mm[i][j];

    __hip_bfloat16* arow = Abuf + (size_t)row * DIM;
#pragma unroll
    for (int j = 0; j < 8; j++) {
        ushort4 u;
        u.x = f2bf(xv[j].x * gpre); u.y = f2bf(xv[j].y * gpre);
        u.z = f2bf(xv[j].z * gpre); u.w = f2bf(xv[j].w * gpre);
        *reinterpret_cast<ushort4*>(arow + (j * 64 + lane) * 4) = u;
    }
    if (lane == 0) {
        g_res_arr[row]  = gres;
        g_post_arr[row] = gpost;
    }
}

// ---------------------------------------------------------------------------
// 256x256 bf16 GEMM — r8/r9 unit-ring with ONE barrier per phase.
//   C[M][N] = A[M][K] @ Bt[N][K]^T; 8 waves (2M x 4N); per-wave out 128x64;
//   BK=64; LDS 128 KiB = 2 parities x {A0,A1,B0,B1} 16 KB units.
// Units: A0: rows {0-63,128-191} [a0] | A1: rows {64-127,192-255} [a1]
//        B0: cols {0-31,64-95,128-159,192-223} [b0] | B1: +32 [b1]
// Unit region [128 rows][128 B], byte col ^ ((row&7)<<4); global_load_lds
// writes linearly, inverse XOR pre-applied on the per-lane global source.
//
// Phase = { ds_reads; 1 stage; [waitcnts]; BAR; LGKM0; MFMA }   (no bar2)
//   P1: rd a0(t)+b0(t); stg B1(t+1); LGKM8; BAR; LGKM0; MFMA(a0,b0)
//   P2: rd b1(t);       stg A0(t+2);        BAR; LGKM0; MFMA(a0,b1)
//   P3: rd a1(t);       stg B0(t+2);        BAR; LGKM0; MFMA(a1,b0)
//   P4:                 stg A1(t+2); VM(6|0); BAR;      MFMA(a1,b1)
// Single-barrier safety: per wave, LGKM0(p) < MFMA(p) < BAR(p+1). A wave
// stages unit U only after BAR(q); every wave crossing BAR(q) has executed
// LGKM0 of the phase where it read U (q >= read-phase + 1) -> WAR safe.
//   A0(t): rd P1(t), pin LGKM0@P1, ovw after BAR(P2).   B0(t): rd P1, pin
//   @P1, ovw after BAR(P3).  B1(t): rd P2, pin @P2, ovw after BAR(P1,t+1).
//   A1(t): rd P3, pin @P3, ovw after BAR(P4).
// RAW/vmcnt: VM(6)@P4(t) drains all of tile t+1 ({A0,B0,A1} from t's ring +
// B1@P1(t)), keeping {A0,B0,A1}(t+2) in flight; tile t+1's reads all occur
// after BAR(P4,t). Prologue VM(6) lands tile0, leaves {A0,B0,A1}(1) in
// flight. Tail: VM(0) when t+2 >= nk; stage macros self-guard.
// ---------------------------------------------------------------------------
#define RD_A(DST, REG)                                                            \
    _Pragma("unroll") for (int m = 0; m < 4; ++m) {                               \
        DST[m][0] = *(const bf16x8*)((REG) + baseA + m * 2048 + cb0);             \
        DST[m][1] = *(const bf16x8*)((REG) + baseA + m * 2048 + cb1);             \
    }
#define RD_B(DST, REG)                                                            \
    _Pragma("unroll") for (int n = 0; n < 2; ++n) {                               \
        DST[n][0] = *(const bf16x8*)((REG) + baseB + n * 2048 + cb0);             \
        DST[n][1] = *(const bf16x8*)((REG) + baseB + n * 2048 + cb1);             \
    }

#define MQ(AF, BF, MO, NO)                                                        \
    __builtin_amdgcn_s_setprio(1);                                                \
    _Pragma("unroll") for (int m = 0; m < 4; ++m)                                 \
    _Pragma("unroll") for (int n = 0; n < 2; ++n) {                               \
        acc[(MO) + m][(NO) + n] = __builtin_amdgcn_mfma_f32_16x16x32_bf16(        \
            AF[m][0], BF[n][0], acc[(MO) + m][(NO) + n], 0, 0, 0);                \
        acc[(MO) + m][(NO) + n] = __builtin_amdgcn_mfma_f32_16x16x32_bf16(        \
            AF[m][1], BF[n][1], acc[(MO) + m][(NO) + n], 0, 0, 0);                \
    }                                                                             \
    __builtin_amdgcn_s_setprio(0);

#define STG_A(t_, h_)                                                             \
    if ((t_) < nk) {                                                              \
        char* l_ = ldsA + (((t_) & 1) * 32768) + (h_) * 16384 + wave * 1024;      \
        async_copy16(Ab + aOff[0][h_] + (size_t)(t_) * 128, l_);                  \
        async_copy16(Ab + aOff[1][h_] + (size_t)(t_) * 128, l_ + 8192);           \
    }
#define STG_B(t_, h_)                                                             \
    if ((t_) < nk) {                                                              \
        char* l_ = ldsB + (((t_) & 1) * 32768) + (h_) * 16384 + wave * 1024;      \
        async_copy16(Bb + bOff[0][h_] + (size_t)(t_) * 128, l_);                  \
        async_copy16(Bb + bOff[1][h_] + (size_t)(t_) * 128, l_ + 8192);           \
    }

template <int MODE, int NB>
__global__ __launch_bounds__(512, 2) void gemm256(
    const __hip_bfloat16* __restrict__ A, const __hip_bfloat16* __restrict__ Bt,
    int M, int N, int K, const float* __restrict__ bias,
    __hip_bfloat16* __restrict__ outh, float* __restrict__ outf,
    const float* __restrict__ x, const float* __restrict__ g_res,
    const float* __restrict__ g_post) {
    __shared__ __align__(16) char ldsA[65536];
    __shared__ __align__(16) char ldsB[65536];

    // XCD band swizzle: each XCD owns an NB-wide column band of tiles.
    const int wg = blockIdx.x;
    const int xcd = wg & 7;
    const int i = wg >> 3;
    const int nt = xcd * NB + (i % NB);
    const int mt = i / NB;
    const int m0 = mt * 256;
    const int n0 = nt * 256;

    const int tid = threadIdx.x;
    const int lane = tid & 63;
    const int wave = tid >> 6;            // 0..7
    const int wr = wave >> 2;             // 0..1 (M)
    const int wc = wave & 3;              // 0..3 (N)
    const int q = lane >> 4;              // 0..3
    const int rr = lane & 7;

    // ds_read addressing (bytes within a 16 KB unit region)
    const uint32_t cb0 = (uint32_t)((q ^ rr) << 4);         // ks=0
    const uint32_t cb1 = (uint32_t)(((4 + q) ^ rr) << 4);   // ks=1
    const uint32_t baseA = (uint32_t)((wr * 64 + (lane & 15)) * 128);
    const uint32_t baseB = (uint32_t)((wc * 32 + (lane & 15)) * 128);

    // staging source addressing
    const uint32_t scb = (uint32_t)((((lane & 7) ^ ((lane >> 3) & 7))) << 4);
    const int lr = lane >> 3;             // 0..7
    const size_t K2 = (size_t)K * 2;
    size_t aOff[2][2], bOff[2][2];
#pragma unroll
    for (int ii = 0; ii < 2; ++ii)
#pragma unroll
        for (int h = 0; h < 2; ++h) {
            int gA = m0 + wave * 8 + lr + ii * 128 + h * 64;
            int gB = n0 + ((wave >> 2) + 2 * ii) * 64 + h * 32 + (wave & 3) * 8 + lr;
            aOff[ii][h] = (size_t)gA * K2 + scb;
            bOff[ii][h] = (size_t)gB * K2 + scb;
        }
    const char* Ab = (const char*)A;
    const char* Bb = (const char*)Bt;

    f32x4 acc[8][4];
#pragma unroll
    for (int m = 0; m < 8; ++m)
#pragma unroll
        for (int n = 0; n < 4; ++n) acc[m][n] = (f32x4){0.f, 0.f, 0.f, 0.f};

    const int nk = K / 64;

    // Prologue: tile0 {A0,B0,B1,A1} + tile1 {A0,B0,A1}; VM(6) = tile0 done.
    STG_A(0, 0); STG_B(0, 0); STG_B(0, 1); STG_A(0, 1);
    STG_A(1, 0); STG_B(1, 0); STG_A(1, 1);
    VM(6);
    wg_barrier();

    bf16x8 a0[4][2], a1[4][2];
    bf16x8 b0[2][2], b1[2][2];

    for (int kt = 0; kt < nk; ++kt) {
        const int c = kt & 1;
        const char* Ac = ldsA + c * 32768;
        const char* Bc = ldsB + c * 32768;
        // ---- P1: rd a0(t)+b0(t); stg B1(t+1)
        RD_A(a0, Ac)
        RD_B(b0, Bc)
        STG_B(kt + 1, 1)
        LGKM8;
        wg_barrier();
        LGKM0;
        MQ(a0, b0, 0, 0)
        // ---- P2: rd b1(t); stg A0(t+2)
        RD_B(b1, Bc + 16384)
        STG_A(kt + 2, 0)
        wg_barrier();
        LGKM0;
        MQ(a0, b1, 0, 2)
        // ---- P3: rd a1(t); stg B0(t+2)
        RD_A(a1, Ac + 16384)
        STG_B(kt + 2, 0)
        wg_barrier();
        LGKM0;
        MQ(a1, b0, 4, 0)
        // ---- P4: stg A1(t+2); per-tile counted vmcnt
        STG_A(kt + 2, 1)
        if (kt + 2 < nk) { VM(6); } else { VM(0); }
        wg_barrier();
        MQ(a1, b1, 4, 2)
    }

    // Epilogue. Row/col mapping follows the interleaved unit layout:
    //   rows:  m0 + wr*128 + (mi>>2)*64 + (mi&3)*16 + q*4 + j
    //   cols:  n0 + wc*64  + (ni>>1)*32 + (ni&1)*16 + (lane&15)
#pragma unroll
    for (int mi = 0; mi < 8; ++mi) {
#pragma unroll
        for (int ni = 0; ni < 4; ++ni) {
            const int col = n0 + wc * 64 + (ni >> 1) * 32 + (ni & 1) * 16 + (lane & 15);
            const float bc = bias[col];
#pragma unroll
            for (int j = 0; j < 4; ++j) {
                const int row = m0 + wr * 128 + (mi >> 2) * 64 + (mi & 3) * 16 + q * 4 + j;
                float v = acc[mi][ni][j] + bc;
                if (MODE == 1) {
                    // tanh-form GELU via fast exp (max dev vs erf-GELU ~3e-4)
                    float u = 1.5957691216057308f * (v + 0.044715f * v * v * v);
                    float s = 1.0f / (1.0f + __expf(-u));
                    outh[(size_t)row * N + col] = __float2bfloat16(v * s);
                } else {
                    outf[(size_t)row * N + col] =
                        x[(size_t)row * N + col] * g_res[row] + v * g_post[row];
                }
            }
        }
    }
}

// ---------------------------------------------------------------------------
// Workspace layout (~235.2 MB): W1T, W2T, Abuf, Hbuf, Wfold, gres, gpost
// ---------------------------------------------------------------------------
extern "C" void kernel_launch(void* const* d_in, const int* in_sizes, int n_in,
                              void* d_out, int out_size, void* d_ws, size_t ws_size,
                              hipStream_t stream) {
    const float* x          = (const float*)d_in[0];
    const float* phi_pre_w  = (const float*)d_in[1];
    const float* phi_pre_b  = (const float*)d_in[2];
    const float* phi_post_w = (const float*)d_in[3];
    const float* phi_post_b = (const float*)d_in[4];
    const float* phi_res_w  = (const float*)d_in[5];
    const float* phi_res_b  = (const float*)d_in[6];
    const float* alpha_pre  = (const float*)d_in[7];
    const float* alpha_post = (const float*)d_in[8];
    const float* alpha_res  = (const float*)d_in[9];
    const float* b_pre      = (const float*)d_in[10];
    const float* b_post     = (const float*)d_in[11];
    const float* b_res      = (const float*)d_in[12];
    const float* W1         = (const float*)d_in[13];
    const float* b1         = (const float*)d_in[14];
    const float* W2         = (const float*)d_in[15];
    const float* b2         = (const float*)d_in[16];
    float* out = (float*)d_out;

    char* ws = (char*)d_ws;
    __hip_bfloat16* W1T  = (__hip_bfloat16*)ws;                      // [DFF][DIM]
    __hip_bfloat16* W2T  = W1T + (size_t)DFF * DIM;                  // [DIM][DFF]
    __hip_bfloat16* Abuf = W2T + (size_t)DIM * DFF;                  // [NROWS][DIM]
    __hip_bfloat16* Hbuf = Abuf + (size_t)NROWS * DIM;               // [NROWS][DFF]
    float* Wfold = (float*)(Hbuf + (size_t)NROWS * DFF);             // [24][DIM]
    float* gres  = Wfold + NFOLD * DIM;
    float* gpost = gres + NROWS;

    fold_kernel<<<(NFOLD * DIM + 255) / 256, 256, 0, stream>>>(phi_pre_w, phi_post_w,
                                                               phi_res_w, Wfold);
    transpose_to_bf16<<<dim3(DFF / 32, DIM / 32), 256, 0, stream>>>(W1, W1T, DIM, DFF);
    transpose_to_bf16<<<dim3(DIM / 32, DFF / 32), 256, 0, stream>>>(W2, W2T, DFF, DIM);
    gating_kernel<<<NROWS / 8, 512, 0, stream>>>(x, Wfold, phi_pre_b, phi_post_b, phi_res_b,
                                                 alpha_pre, alpha_post, alpha_res,
                                                 b_pre, b_post, b_res, Abuf, gres, gpost);
    // GEMM1: [8192 x 2048] @ W1 -> gelu -> Hbuf [8192 x 8192]; grid 32x32=1024, NB=4
    gemm256<1, 4><<<1024, 512, 0, stream>>>(
        Abuf, W1T, NROWS, DFF, DIM, b1, Hbuf, nullptr, nullptr, nullptr, nullptr);
    // GEMM2: [8192 x 8192] @ W2 -> out [8192 x 2048]; grid 32x8=256, NB=1
    gemm256<2, 1><<<256, 512, 0, stream>>>(
        Hbuf, W2T, NROWS, DIM, DFF, b2, nullptr, out, x, gres, gpost);
}

// Round 17
// 630.289 us; speedup vs baseline: 5.3403x; 1.0156x over previous
//
#include <hip/hip_runtime.h>
#include <hip/hip_bf16.h>
#include <cstdint>
#include <cstddef>

// Problem constants (B=4, T=2048, DIM=2048, S=4, DFF=8192)
#define DIM   2048
#define DFF   8192
#define NROWS 8192   // B*T
#define NFOLD 24     // 4 (pre) + 4 (post) + 16 (res)

typedef float f32x4 __attribute__((ext_vector_type(4)));
typedef __bf16 bf16x8 __attribute__((ext_vector_type(8)));

__device__ __forceinline__ float sigmoidf_(float v) { return 1.0f / (1.0f + expf(-v)); }

__device__ __forceinline__ unsigned short f2bf(float v) {
    union { __hip_bfloat16 h; unsigned short u; } cv;
    cv.h = __float2bfloat16(v);
    return cv.u;
}

__device__ __forceinline__ void async_copy16(const void* g, void* l) {
    __builtin_amdgcn_global_load_lds((const __attribute__((address_space(1))) void*)g,
                                     (__attribute__((address_space(3))) void*)l, 16, 0, 0);
}

// Raw workgroup barrier WITHOUT waitcnt drain (keeps global_load_lds in flight).
__device__ __forceinline__ void wg_barrier() {
    asm volatile("" ::: "memory");
    __builtin_amdgcn_s_barrier();
    asm volatile("" ::: "memory");
}

#define VM(n)  asm volatile("s_waitcnt vmcnt(" #n ")" ::: "memory")
#define LGKM0  asm volatile("s_waitcnt lgkmcnt(0)" ::: "memory")
// ROUND 17: continue the barrier-reduction direction that won in r16
// (8->4 barriers/tile: 295->274us, MfmaUtil 41->45%). Now 4->2 barriers/
// tile: merge P1+P2 and P3+P4 into two phases with 32-MFMA clusters.
// Longer skew windows: fast waves' read bursts (16/8 ds_reads) drain on the
// LDS port while slow waves are still inside the previous 32-MFMA cluster.

// ---------------------------------------------------------------------------
// Fold phi weights: Wfold[r][d] = sum_{j<4} src[r][j*DIM + d], r in [0,24)
// ---------------------------------------------------------------------------
__global__ __launch_bounds__(256) void fold_kernel(const float* __restrict__ pre_w,
                                                   const float* __restrict__ post_w,
                                                   const float* __restrict__ res_w,
                                                   float* __restrict__ Wfold) {
    int idx = blockIdx.x * 256 + threadIdx.x;
    if (idx >= NFOLD * DIM) return;
    int r = idx >> 11;          // /DIM
    int d = idx & (DIM - 1);
    const float* src;
    if (r < 4)      src = pre_w  + (size_t)r * (4 * DIM);
    else if (r < 8) src = post_w + (size_t)(r - 4) * (4 * DIM);
    else            src = res_w  + (size_t)(r - 8) * (4 * DIM);
    Wfold[idx] = src[d] + src[DIM + d] + src[2 * DIM + d] + src[3 * DIM + d];
}

// ---------------------------------------------------------------------------
// Transpose f32 [R][C] -> bf16 [C][R]
// ---------------------------------------------------------------------------
__global__ __launch_bounds__(256) void transpose_to_bf16(const float* __restrict__ in,
                                                         __hip_bfloat16* __restrict__ out,
                                                         int R, int C) {
    __shared__ float tile[32][33];
    int bx = blockIdx.x, by = blockIdx.y;
    int tx = threadIdx.x & 31, ty0 = threadIdx.x >> 5;
#pragma unroll
    for (int i = 0; i < 4; i++) {
        int ty = ty0 + i * 8;
        tile[ty][tx] = in[(size_t)(by * 32 + ty) * C + bx * 32 + tx];
    }
    __syncthreads();
#pragma unroll
    for (int i = 0; i < 4; i++) {
        int ty = ty0 + i * 8;
        out[(size_t)(bx * 32 + ty) * R + by * 32 + tx] = __float2bfloat16(tile[tx][ty]);
    }
}

// ---------------------------------------------------------------------------
// Gating: wave-per-row, 8 rows per block (512 threads).
// ---------------------------------------------------------------------------
__global__ __launch_bounds__(512) void gating_kernel(
    const float* __restrict__ x, const float* __restrict__ Wfold,
    const float* __restrict__ phi_pre_b, const float* __restrict__ phi_post_b,
    const float* __restrict__ phi_res_b,
    const float* __restrict__ alpha_pre, const float* __restrict__ alpha_post,
    const float* __restrict__ alpha_res,
    const float* __restrict__ b_pre, const float* __restrict__ b_post,
    const float* __restrict__ b_res,
    __hip_bfloat16* __restrict__ Abuf,
    float* __restrict__ g_res_arr, float* __restrict__ g_post_arr) {
    const int tid = threadIdx.x;
    const int lane = tid & 63, wave = tid >> 6;
    const int row = blockIdx.x * 8 + wave;

    const float4* x4 = (const float4*)x + (size_t)row * 512;
    const float4* w4 = (const float4*)Wfold;

    float4 xv[8];
#pragma unroll
    for (int j = 0; j < 8; j++) xv[j] = x4[j * 64 + lane];

    float p[25];
    p[24] = 0.f;
#pragma unroll
    for (int j = 0; j < 8; j++)
        p[24] += xv[j].x * xv[j].x + xv[j].y * xv[j].y + xv[j].z * xv[j].z + xv[j].w * xv[j].w;

    for (int r = 0; r < NFOLD; r++) {
        float acc = 0.f;
#pragma unroll
        for (int j = 0; j < 8; j++) {
            float4 wv = w4[r * 512 + j * 64 + lane];
            acc += xv[j].x * wv.x + xv[j].y * wv.y + xv[j].z * wv.z + xv[j].w * wv.w;
        }
        p[r] = acc;
    }

#pragma unroll
    for (int r = 0; r < 25; r++) {
        float v = p[r];
#pragma unroll
        for (int off = 1; off < 64; off <<= 1) v += __shfl_xor(v, off, 64);
        p[r] = v;
    }

    const float rms = rsqrtf(p[24] / (float)DIM + 1.1920928955078125e-07f);
    const float ap = alpha_pre[0], aq = alpha_post[0], ar = alpha_res[0];
    float gpre = 0.f, gpost = 0.f;
#pragma unroll
    for (int s = 0; s < 4; s++) {
        gpre  += sigmoidf_(ap * (rms * p[s]     + phi_pre_b[s])  + b_pre[s]);
        gpost += 2.0f * sigmoidf_(aq * (rms * p[4 + s] + phi_post_b[s]) + b_post[s]);
    }
    float Mm[4][4];
#pragma unroll
    for (int i = 0; i < 4; i++)
#pragma unroll
        for (int j = 0; j < 4; j++) {
            int k = i * 4 + j;
            Mm[i][j] = expf(ar * (rms * p[8 + k] + phi_res_b[k]) + b_res[k]);
        }
    for (int it = 0; it < 10; ++it) {
#pragma unroll
        for (int i = 0; i < 4; i++) {
            float rs = 1.0f / (Mm[i][0] + Mm[i][1] + Mm[i][2] + Mm[i][3]);
#pragma unroll
            for (int j = 0; j < 4; j++) Mm[i][j] *= rs;
        }
#pragma unroll
        for (int j = 0; j < 4; j++) {
            float cs = 1.0f / (Mm[0][j] + Mm[1][j] + Mm[2][j] + Mm[3][j]);
#pragma unroll
            for (int i = 0; i < 4; i++) Mm[i][j] *= cs;
        }
    }
    float gres = 0.f;
#pragma unroll
    for (int i = 0; i < 4; i++)
#pragma unroll
        for (int j = 0; j < 4; j++) gres += Mm[i][j];

    __hip_bfloat16* arow = Abuf + (size_t)row * DIM;
#pragma unroll
    for (int j = 0; j < 8; j++) {
        ushort4 u;
        u.x = f2bf(xv[j].x * gpre); u.y = f2bf(xv[j].y * gpre);
        u.z = f2bf(xv[j].z * gpre); u.w = f2bf(xv[j].w * gpre);
        *reinterpret_cast<ushort4*>(arow + (j * 64 + lane) * 4) = u;
    }
    if (lane == 0) {
        g_res_arr[row]  = gres;
        g_post_arr[row] = gpost;
    }
}

// ---------------------------------------------------------------------------
// 256x256 bf16 GEMM — unit-ring with TWO barriers per K-tile.
//   C[M][N] = A[M][K] @ Bt[N][K]^T; 8 waves (2M x 4N); per-wave out 128x64;
//   BK=64; LDS 128 KiB = 2 parities x {A0,A1,B0,B1} 16 KB units.
// Units: A0: rows {0-63,128-191} [a0] | A1: rows {64-127,192-255} [a1]
//        B0: cols {0-31,64-95,128-159,192-223} [b0] | B1: +32 [b1]
// Unit region [128 rows][128 B], byte col ^ ((row&7)<<4); global_load_lds
// writes linearly, inverse XOR pre-applied on the per-lane global source.
//
// Phase = { ds_reads; stages; [VM]; BAR; LGKM0; 32 MFMA }  (one bar/phase)
//   Ph1: rd a0,b0,b1(t)[16]; stg A1(t+1),B1(t+1);        BAR; LGKM0;
//        MFMA(a0,b0)+(a0,b1)
//   Ph2: rd a1(t)[8];        stg A0(t+2),B0(t+2); VM(4|0); BAR; LGKM0;
//        MFMA(a1,b0)+(a1,b1)
// WAR (read -> pin -> overwrite): A0/B0(t) rd Ph1 pre-bar, pinned LGKM0
//   post-bar(Ph1), ovw staged in Ph2 body (post-bar(Ph1)) — same one-barrier
//   + latency-margin structure r16 validated. A1(t) rd Ph2(t) pre-bar, ovw
//   A1(t+1) staged Ph1(t+1) body (post-bar(Ph2,t)). B1(t) rd Ph1(t), ovw
//   staged Ph1(t+1) — two barriers. b0 regs live Ph1(t)->Ph2(t) (consumed by
//   MFMA(a1,b0)), re-read Ph1(t+1).
// RAW/vmcnt FIFO (loads, 2/stage): steady entering Ph1(t): outstanding =
//   {A0,B0}(t+1)[4]. Ph1 +{A1,B1}(t+1) -> 8; Ph2 +{A0,B0}(t+2) -> 12;
//   VM(4) keeps {A0,B0}(t+2), drains ALL of tile t+1 before bar -> Ph1(t+1)
//   reads are safe. Prologue: stg t0{A0,B0,B1,A1} + {A0,B0}(1); VM(4) lands
//   tile0, leaves {A0,B0}(1) in flight = the invariant.
// Tail: kt >= nk-2 -> VM(0); stage macros self-guard (t < nk).
// ---------------------------------------------------------------------------
#define RD_A(DST, REG)                                                            \
    _Pragma("unroll") for (int m = 0; m < 4; ++m) {                               \
        DST[m][0] = *(const bf16x8*)((REG) + baseA + m * 2048 + cb0);             \
        DST[m][1] = *(const bf16x8*)((REG) + baseA + m * 2048 + cb1);             \
    }
#define RD_B(DST, REG)                                                            \
    _Pragma("unroll") for (int n = 0; n < 2; ++n) {                               \
        DST[n][0] = *(const bf16x8*)((REG) + baseB + n * 2048 + cb0);             \
        DST[n][1] = *(const bf16x8*)((REG) + baseB + n * 2048 + cb1);             \
    }

#define MQ(AF, BF, MO, NO)                                                        \
    __builtin_amdgcn_s_setprio(1);                                                \
    _Pragma("unroll") for (int m = 0; m < 4; ++m)                                 \
    _Pragma("unroll") for (int n = 0; n < 2; ++n) {                               \
        acc[(MO) + m][(NO) + n] = __builtin_amdgcn_mfma_f32_16x16x32_bf16(        \
            AF[m][0], BF[n][0], acc[(MO) + m][(NO) + n], 0, 0, 0);                \
        acc[(MO) + m][(NO) + n] = __builtin_amdgcn_mfma_f32_16x16x32_bf16(        \
            AF[m][1], BF[n][1], acc[(MO) + m][(NO) + n], 0, 0, 0);                \
    }                                                                             \
    __builtin_amdgcn_s_setprio(0);

#define STG_A(t_, h_)                                                             \
    if ((t_) < nk) {                                                              \
        char* l_ = ldsA + (((t_) & 1) * 32768) + (h_) * 16384 + wave * 1024;      \
        async_copy16(Ab + aOff[0][h_] + (size_t)(t_) * 128, l_);                  \
        async_copy16(Ab + aOff[1][h_] + (size_t)(t_) * 128, l_ + 8192);           \
    }
#define STG_B(t_, h_)                                                             \
    if ((t_) < nk) {                                                              \
        char* l_ = ldsB + (((t_) & 1) * 32768) + (h_) * 16384 + wave * 1024;      \
        async_copy16(Bb + bOff[0][h_] + (size_t)(t_) * 128, l_);                  \
        async_copy16(Bb + bOff[1][h_] + (size_t)(t_) * 128, l_ + 8192);           \
    }

template <int MODE, int NB>
__global__ __launch_bounds__(512, 2) void gemm256(
    const __hip_bfloat16* __restrict__ A, const __hip_bfloat16* __restrict__ Bt,
    int M, int N, int K, const float* __restrict__ bias,
    __hip_bfloat16* __restrict__ outh, float* __restrict__ outf,
    const float* __restrict__ x, const float* __restrict__ g_res,
    const float* __restrict__ g_post) {
    __shared__ __align__(16) char ldsA[65536];
    __shared__ __align__(16) char ldsB[65536];

    // XCD band swizzle: each XCD owns an NB-wide column band of tiles.
    const int wg = blockIdx.x;
    const int xcd = wg & 7;
    const int i = wg >> 3;
    const int nt = xcd * NB + (i % NB);
    const int mt = i / NB;
    const int m0 = mt * 256;
    const int n0 = nt * 256;

    const int tid = threadIdx.x;
    const int lane = tid & 63;
    const int wave = tid >> 6;            // 0..7
    const int wr = wave >> 2;             // 0..1 (M)
    const int wc = wave & 3;              // 0..3 (N)
    const int q = lane >> 4;              // 0..3
    const int rr = lane & 7;

    // ds_read addressing (bytes within a 16 KB unit region)
    const uint32_t cb0 = (uint32_t)((q ^ rr) << 4);         // ks=0
    const uint32_t cb1 = (uint32_t)(((4 + q) ^ rr) << 4);   // ks=1
    const uint32_t baseA = (uint32_t)((wr * 64 + (lane & 15)) * 128);
    const uint32_t baseB = (uint32_t)((wc * 32 + (lane & 15)) * 128);

    // staging source addressing
    const uint32_t scb = (uint32_t)((((lane & 7) ^ ((lane >> 3) & 7))) << 4);
    const int lr = lane >> 3;             // 0..7
    const size_t K2 = (size_t)K * 2;
    size_t aOff[2][2], bOff[2][2];
#pragma unroll
    for (int ii = 0; ii < 2; ++ii)
#pragma unroll
        for (int h = 0; h < 2; ++h) {
            int gA = m0 + wave * 8 + lr + ii * 128 + h * 64;
            int gB = n0 + ((wave >> 2) + 2 * ii) * 64 + h * 32 + (wave & 3) * 8 + lr;
            aOff[ii][h] = (size_t)gA * K2 + scb;
            bOff[ii][h] = (size_t)gB * K2 + scb;
        }
    const char* Ab = (const char*)A;
    const char* Bb = (const char*)Bt;

    f32x4 acc[8][4];
#pragma unroll
    for (int m = 0; m < 8; ++m)
#pragma unroll
        for (int n = 0; n < 4; ++n) acc[m][n] = (f32x4){0.f, 0.f, 0.f, 0.f};

    const int nk = K / 64;

    // Prologue: tile0 {A0,B0,B1,A1} + {A0,B0}(1); VM(4) = tile0 landed,
    // {A0,B0}(1) in flight (the loop invariant).
    STG_A(0, 0); STG_B(0, 0); STG_B(0, 1); STG_A(0, 1);
    STG_A(1, 0); STG_B(1, 0);
    VM(4);
    wg_barrier();

    bf16x8 a0[4][2], a1[4][2];
    bf16x8 b0[2][2], b1[2][2];

    for (int kt = 0; kt < nk; ++kt) {
        const int c = kt & 1;
        const char* Ac = ldsA + c * 32768;
        const char* Bc = ldsB + c * 32768;
        // ---- Ph1: rd a0,b0,b1(t); stg A1(t+1),B1(t+1)
        RD_A(a0, Ac)
        RD_B(b0, Bc)
        RD_B(b1, Bc + 16384)
        STG_A(kt + 1, 1)
        STG_B(kt + 1, 1)
        wg_barrier();
        LGKM0;
        MQ(a0, b0, 0, 0)
        MQ(a0, b1, 0, 2)
        // ---- Ph2: rd a1(t); stg A0(t+2),B0(t+2); VM(4|0)
        RD_A(a1, Ac + 16384)
        STG_A(kt + 2, 0)
        STG_B(kt + 2, 0)
        if (kt + 2 < nk) { VM(4); } else { VM(0); }
        wg_barrier();
        LGKM0;
        MQ(a1, b0, 4, 0)
        MQ(a1, b1, 4, 2)
    }

    // Epilogue. Row/col mapping follows the interleaved unit layout:
    //   rows:  m0 + wr*128 + (mi>>2)*64 + (mi&3)*16 + q*4 + j
    //   cols:  n0 + wc*64  + (ni>>1)*32 + (ni&1)*16 + (lane&15)
#pragma unroll
    for (int mi = 0; mi < 8; ++mi) {
#pragma unroll
        for (int ni = 0; ni < 4; ++ni) {
            const int col = n0 + wc * 64 + (ni >> 1) * 32 + (ni & 1) * 16 + (lane & 15);
            const float bc = bias[col];
#pragma unroll
            for (int j = 0; j < 4; ++j) {
                const int row = m0 + wr * 128 + (mi >> 2) * 64 + (mi & 3) * 16 + q * 4 + j;
                float v = acc[mi][ni][j] + bc;
                if (MODE == 1) {
                    // tanh-form GELU via fast exp (max dev vs erf-GELU ~3e-4)
                    float u = 1.5957691216057308f * (v + 0.044715f * v * v * v);
                    float s = 1.0f / (1.0f + __expf(-u));
                    outh[(size_t)row * N + col] = __float2bfloat16(v * s);
                } else {
                    outf[(size_t)row * N + col] =
                        x[(size_t)row * N + col] * g_res[row] + v * g_post[row];
                }
            }
        }
    }
}

// ---------------------------------------------------------------------------
// Workspace layout (~235.2 MB): W1T, W2T, Abuf, Hbuf, Wfold, gres, gpost
// ---------------------------------------------------------------------------
extern "C" void kernel_launch(void* const* d_in, const int* in_sizes, int n_in,
                              void* d_out, int out_size, void* d_ws, size_t ws_size,
                              hipStream_t stream) {
    const float* x          = (const float*)d_in[0];
    const float* phi_pre_w  = (const float*)d_in[1];
    const float* phi_pre_b  = (const float*)d_in[2];
    const float* phi_post_w = (const float*)d_in[3];
    const float* phi_post_b = (const float*)d_in[4];
    const float* phi_res_w  = (const float*)d_in[5];
    const float* phi_res_b  = (const float*)d_in[6];
    const float* alpha_pre  = (const float*)d_in[7];
    const float* alpha_post = (const float*)d_in[8];
    const float* alpha_res  = (const float*)d_in[9];
    const float* b_pre      = (const float*)d_in[10];
    const float* b_post     = (const float*)d_in[11];
    const float* b_res      = (const float*)d_in[12];
    const float* W1         = (const float*)d_in[13];
    const float* b1         = (const float*)d_in[14];
    const float* W2         = (const float*)d_in[15];
    const float* b2         = (const float*)d_in[16];
    float* out = (float*)d_out;

    char* ws = (char*)d_ws;
    __hip_bfloat16* W1T  = (__hip_bfloat16*)ws;                      // [DFF][DIM]
    __hip_bfloat16* W2T  = W1T + (size_t)DFF * DIM;                  // [DIM][DFF]
    __hip_bfloat16* Abuf = W2T + (size_t)DIM * DFF;                  // [NROWS][DIM]
    __hip_bfloat16* Hbuf = Abuf + (size_t)NROWS * DIM;               // [NROWS][DFF]
    float* Wfold = (float*)(Hbuf + (size_t)NROWS * DFF);             // [24][DIM]
    float* gres  = Wfold + NFOLD * DIM;
    float* gpost = gres + NROWS;

    fold_kernel<<<(NFOLD * DIM + 255) / 256, 256, 0, stream>>>(phi_pre_w, phi_post_w,
                                                               phi_res_w, Wfold);
    transpose_to_bf16<<<dim3(DFF / 32, DIM / 32), 256, 0, stream>>>(W1, W1T, DIM, DFF);
    transpose_to_bf16<<<dim3(DIM / 32, DFF / 32), 256, 0, stream>>>(W2, W2T, DFF, DIM);
    gating_kernel<<<NROWS / 8, 512, 0, stream>>>(x, Wfold, phi_pre_b, phi_post_b, phi_res_b,
                                                 alpha_pre, alpha_post, alpha_res,
                                                 b_pre, b_post, b_res, Abuf, gres, gpost);
    // GEMM1: [8192 x 2048] @ W1 -> gelu -> Hbuf [8192 x 8192]; grid 32x32=1024, NB=4
    gemm256<1, 4><<<1024, 512, 0, stream>>>(
        Abuf, W1T, NROWS, DFF, DIM, b1, Hbuf, nullptr, nullptr, nullptr, nullptr);
    // GEMM2: [8192 x 8192] @ W2 -> out [8192 x 2048]; grid 32x8=256, NB=1
    gemm256<2, 1><<<256, 512, 0, stream>>>(
        Hbuf, W2T, NROWS, DIM, DFF, b2, nullptr, out, x, gres, gpost);
}